// Round 4
// baseline (394.747 us; speedup 1.0000x reference)
//
#include <hip/hip_runtime.h>

// Problem constants
#define BATCH 64
#define CIN   128
#define HIN   56
#define WIN   56
#define COUT  256
#define KSZ   3
#define OHP   54
#define OWP   54
#define NSPAT (OHP * OWP)            // 2916 flat spatial outputs per batch
#define NFLAT (BATCH * NSPAT)        // 186624 = 729 * 256 exactly
#define KDIM  (CIN * KSZ * KSZ)      // 1152 = 18 * 64
#define NBLK  (NFLAT / 256)          // 729 conv blocks (256x256 tiles)

typedef short bf16x8 __attribute__((ext_vector_type(8)));
typedef float f32x4  __attribute__((ext_vector_type(4)));

static __device__ __forceinline__ unsigned short f2bf(float f) {
    unsigned v = __float_as_uint(f);
    v += 0x7FFFu + ((v >> 16) & 1u);
    return (unsigned short)(v >> 16);
}

static __device__ __forceinline__ void gl_lds16(const void* g, void* l) {
    __builtin_amdgcn_global_load_lds(
        (const __attribute__((address_space(1))) void*)g,
        (__attribute__((address_space(3))) void*)l, 16, 0, 0);
}

// Raw barrier + counted vmcnt (no __syncthreads: it drains vmcnt(0) with zero cover).
#define BAR()   asm volatile("s_barrier" ::: "memory")
#define VMC8()  asm volatile("s_waitcnt vmcnt(8)" ::: "memory")
#define VMC0()  asm volatile("s_waitcnt vmcnt(0)" ::: "memory")

// ---------------- kernel 1: per-block max |w| ----------------
__global__ __launch_bounds__(256) void maxabs_kernel(const float* __restrict__ w,
                                                     float* __restrict__ blockmax, int n) {
    float m = 0.f;
    for (int i = blockIdx.x * 256 + threadIdx.x; i < n; i += gridDim.x * 256)
        m = fmaxf(m, fabsf(w[i]));
    for (int off = 32; off > 0; off >>= 1)
        m = fmaxf(m, __shfl_down(m, off));
    __shared__ float red[4];
    if ((threadIdx.x & 63) == 0) red[threadIdx.x >> 6] = m;
    __syncthreads();
    if (threadIdx.x == 0)
        blockmax[blockIdx.x] = fmaxf(fmaxf(red[0], red[1]), fmaxf(red[2], red[3]));
}

// ---------------- kernel 2: finish max-reduce + ternary quantize + repack ----------------
// qw layout: [co][(kh*3+kw)*128 + ci] bf16
__global__ __launch_bounds__(256) void quant_kernel(const float* __restrict__ w,
                                                    const float* __restrict__ wp,
                                                    const float* __restrict__ wn,
                                                    const float* __restrict__ blockmax,
                                                    unsigned short* __restrict__ qw) {
    __shared__ float red[4];
    float m = blockmax[threadIdx.x];          // 256 partial maxima
    for (int off = 32; off > 0; off >>= 1)
        m = fmaxf(m, __shfl_down(m, off));
    if ((threadIdx.x & 63) == 0) red[threadIdx.x >> 6] = m;
    __syncthreads();
    float t = 0.05f * fmaxf(fmaxf(red[0], red[1]), fmaxf(red[2], red[3]));

    int idx = blockIdx.x * 256 + threadIdx.x;   // grid covers exactly 294912
    float p = fabsf(wp[0]), nn = fabsf(wn[0]);
    float v = w[idx];
    float q = (v > t) ? p : ((v < -t) ? -nn : 0.0f);
    int co  = idx / KDIM;
    int rem = idx - co * KDIM;
    int ci  = rem / 9;
    int kk  = rem - ci * 9;            // kh*3+kw
    qw[co * KDIM + kk * CIN + ci] = f2bf(q);
}

// ---------------- kernel 3: x fp32 NCHW -> bf16 NHWC (x_t[b][h][w][ci]) ----------------
__global__ __launch_bounds__(256) void cast_nhwc_kernel(const float* __restrict__ x,
                                                        unsigned* __restrict__ xt_u32) {
    int b = blockIdx.x / HIN;
    int h = blockIdx.x - b * HIN;
    __shared__ float xs[CIN][57];
#pragma unroll
    for (int it = 0; it < 7; ++it) {
        int id = it * 256 + threadIdx.x;       // 1792 float4 chunks: 128 ci x 14
        int ci = id / 14;
        int wq = (id - ci * 14) * 4;
        float4 v = *(const float4*)(x + (((size_t)(b * CIN + ci)) * HIN + h) * WIN + wq);
        xs[ci][wq + 0] = v.x; xs[ci][wq + 1] = v.y;
        xs[ci][wq + 2] = v.z; xs[ci][wq + 3] = v.w;
    }
    __syncthreads();
#pragma unroll
    for (int it = 0; it < 7; ++it) {
        int id = it * 256 + threadIdx.x;       // 56 w x 32 chunks of 4 ci
        int w_ = id >> 5;
        int cq = (id & 31) * 4;
        unsigned u0 = (unsigned)f2bf(xs[cq + 0][w_]) | ((unsigned)f2bf(xs[cq + 1][w_]) << 16);
        unsigned u1 = (unsigned)f2bf(xs[cq + 2][w_]) | ((unsigned)f2bf(xs[cq + 3][w_]) << 16);
        uint2 val; val.x = u0; val.y = u1;
        *(uint2*)&xt_u32[((size_t)(b * HIN + h) * WIN + w_) * 64 + (id & 31) * 2] = val;
    }
}

// ---------------- kernel 4: implicit-GEMM MFMA conv, 256x256 tile, tile-deep pipeline ----
// BM=256 (all co), BN=256 (flat n, 729*256 exact), BK=64, 18 K-tiles.
// 512 threads = 8 waves (2M x 4N); per-wave 128co x 64n (acc[8][4] f32x4) -> LDS
// reads/MFMA = 1/42.7 vs 1/32 at 128^2 (wave-tile perimeter/area sets the LDS-BW bound).
// LDS: 2 slots x 64 KB dbuf.
//
// Sync design (fixes R1/R2's failure: every wait there was on <=1-phase-old loads and
// phase barriers lockstepped waves):
//   per K-tile t: { stage ALL 8 calls for t+1 into slot nxt   (nxt free since t-1's
//                   end-barrier);
//                   VMC8: retires exactly this wave's 8 tile-t loads, which were
//                   issued ONE FULL TILE (~2500-4000 cy) ago -> zero-cost wait;
//                   BAR:  all waves' tile-t loads confirmed  -> compute may read;
//                   compute: 24 ds_read_b128 + 64 MFMA, NO intra-tile sync -> waves
//                   drift, LDS-read and MFMA windows overlap across waves;
//                   BAR:  compute done -> next iter may overwrite slot nxt }
// Ledger: outstanding/wave = 8 entering iter, 16 after stage, 8 after VMC8. t=17: VMC0
// (tile-17 loads are 1 tile old -> cheap). Addressing/epilogue verbatim from R1/R2
// (correctness-proven, absmax 0.125); only the sync structure differs.
__global__ __launch_bounds__(512, 2) void conv_mfma_kernel(const unsigned short* __restrict__ xt,
                                                           const unsigned short* __restrict__ qw,
                                                           const float* __restrict__ bias,
                                                           float* __restrict__ out) {
    // bijective XCD swizzle (729 = 8*91 + 1)
    unsigned orig = blockIdx.x;
    unsigned xcd = orig & 7u, loc = orig >> 3;
    const unsigned q91 = NBLK / 8u, r1 = NBLK % 8u;  // 91, 1
    unsigned wgid = (xcd < r1 ? xcd * (q91 + 1) : r1 * (q91 + 1) + (xcd - r1) * q91) + loc;
    unsigned n0 = wgid * 256u;

    __shared__ __align__(16) unsigned short sm[2][32768];  // [slot][A:0..16384 | B:16384..32768]

    const int tid   = threadIdx.x;
    const int wave  = tid >> 6, lane = tid & 63;
    const int wrow  = wave >> 2;          // 0..1  (co half)
    const int wcol  = wave & 3;           // 0..3  (n quarter)
    const int quad  = lane >> 4, r16 = lane & 15;
    const int row_s = tid >> 3;                       // staging row within a 64-row call
    const int lc    = (tid & 7) ^ (row_s & 7);        // XOR-8 pre-swizzled source chunk

    const unsigned short* Ag = qw + (size_t)row_s * KDIM + lc * 8;
    const unsigned short* Bg[4];
#pragma unroll
    for (int c = 0; c < 4; ++c) {
        unsigned n = n0 + c * 64 + row_s;
        unsigned b = n / NSPAT, rem = n - b * NSPAT;
        unsigned oh = rem / OWP, ow = rem - oh * OWP;
        Bg[c] = xt + ((size_t)((b * HIN + oh) * WIN + ow)) * CIN + lc * 8;
    }

    auto stA = [&](int slot, int c, int kt) {
        gl_lds16(Ag + (size_t)c * (64 * KDIM) + kt * 64,
                 (char*)sm + slot * 65536 + c * 8192 + wave * 1024);
    };
    auto stB = [&](int slot, int c, int boff) {
        gl_lds16(Bg[c] + boff,
                 (char*)sm + slot * 65536 + 32768 + c * 8192 + wave * 1024);
    };

    f32x4 acc[8][4] = {};

    const int pc0 = (quad ^ (r16 & 7)) * 8;        // phys chunk (shorts), k-half 0
    const int pc1 = ((4 + quad) ^ (r16 & 7)) * 8;  // k-half 1
    const int ar  = wrow * 128 + r16;              // A base row for this lane
    const int br  = wcol * 64  + r16;              // B base row for this lane

#define MROW(I, AF) \
    acc[I][0] = __builtin_amdgcn_mfma_f32_16x16x32_bf16(AF, bfr0, acc[I][0], 0, 0, 0); \
    acc[I][1] = __builtin_amdgcn_mfma_f32_16x16x32_bf16(AF, bfr1, acc[I][1], 0, 0, 0); \
    acc[I][2] = __builtin_amdgcn_mfma_f32_16x16x32_bf16(AF, bfr2, acc[I][2], 0, 0, 0); \
    acc[I][3] = __builtin_amdgcn_mfma_f32_16x16x32_bf16(AF, bfr3, acc[I][3], 0, 0, 0);

    // ---- prologue: stage tile 0 into slot 0; no wait (confirmed inside iter t=0) ----
    {
        stB(0, 0, 0); stB(0, 1, 0); stB(0, 2, 0); stB(0, 3, 0);
        stA(0, 0, 0); stA(0, 1, 0); stA(0, 2, 0); stA(0, 3, 0);
    }

#pragma unroll
    for (int t = 0; t < 18; ++t) {
        const int cur = t & 1, nxt = cur ^ 1;
        const unsigned short* Ac = &sm[cur][0];
        const unsigned short* Bc = &sm[cur][16384];

        // ---- stage tile t+1 (slot nxt free since t-1's end-barrier) ----
        if (t < 17) {
            const int t1  = t + 1;
            const int sl1 = t1 >> 1;
            const int kh1 = sl1 / 3, kw1 = sl1 - 3 * kh1;
            const int boff1 = (kh1 * WIN + kw1) * CIN + (t1 & 1) * 64;   // shorts
            stB(nxt, 0, boff1); stB(nxt, 1, boff1); stB(nxt, 2, boff1); stB(nxt, 3, boff1);
            stA(nxt, 0, t1);    stA(nxt, 1, t1);    stA(nxt, 2, t1);    stA(nxt, 3, t1);
            VMC8();   // retire this wave's tile-t loads (issued one full tile ago)
        } else {
            VMC0();   // last tile: drain (loads are 1 tile old -> cheap)
        }
        BAR();        // all waves' tile-t loads confirmed

        bf16x8 af0, af1, af2, af3, bfr0, bfr1, bfr2, bfr3;

        // ---- compute: no intra-tile sync; waves drift; compiler handles lgkmcnt ----
        // G0: k-half 0, acc rows 0..3
        af0  = *(const bf16x8*)&Ac[(ar +  0) * 64 + pc0];
        af1  = *(const bf16x8*)&Ac[(ar + 16) * 64 + pc0];
        af2  = *(const bf16x8*)&Ac[(ar + 32) * 64 + pc0];
        af3  = *(const bf16x8*)&Ac[(ar + 48) * 64 + pc0];
        bfr0 = *(const bf16x8*)&Bc[(br +  0) * 64 + pc0];
        bfr1 = *(const bf16x8*)&Bc[(br + 16) * 64 + pc0];
        bfr2 = *(const bf16x8*)&Bc[(br + 32) * 64 + pc0];
        bfr3 = *(const bf16x8*)&Bc[(br + 48) * 64 + pc0];
        __builtin_amdgcn_s_setprio(1);
        MROW(0, af0) MROW(1, af1) MROW(2, af2) MROW(3, af3)
        __builtin_amdgcn_s_setprio(0);

        // G1: k-half 0, acc rows 4..7 (reuse bfr)
        af0 = *(const bf16x8*)&Ac[(ar +  64) * 64 + pc0];
        af1 = *(const bf16x8*)&Ac[(ar +  80) * 64 + pc0];
        af2 = *(const bf16x8*)&Ac[(ar +  96) * 64 + pc0];
        af3 = *(const bf16x8*)&Ac[(ar + 112) * 64 + pc0];
        __builtin_amdgcn_s_setprio(1);
        MROW(4, af0) MROW(5, af1) MROW(6, af2) MROW(7, af3)
        __builtin_amdgcn_s_setprio(0);

        // G2: k-half 1, acc rows 0..3
        af0  = *(const bf16x8*)&Ac[(ar +  0) * 64 + pc1];
        af1  = *(const bf16x8*)&Ac[(ar + 16) * 64 + pc1];
        af2  = *(const bf16x8*)&Ac[(ar + 32) * 64 + pc1];
        af3  = *(const bf16x8*)&Ac[(ar + 48) * 64 + pc1];
        bfr0 = *(const bf16x8*)&Bc[(br +  0) * 64 + pc1];
        bfr1 = *(const bf16x8*)&Bc[(br + 16) * 64 + pc1];
        bfr2 = *(const bf16x8*)&Bc[(br + 32) * 64 + pc1];
        bfr3 = *(const bf16x8*)&Bc[(br + 48) * 64 + pc1];
        __builtin_amdgcn_s_setprio(1);
        MROW(0, af0) MROW(1, af1) MROW(2, af2) MROW(3, af3)
        __builtin_amdgcn_s_setprio(0);

        // G3: k-half 1, acc rows 4..7
        af0 = *(const bf16x8*)&Ac[(ar +  64) * 64 + pc1];
        af1 = *(const bf16x8*)&Ac[(ar +  80) * 64 + pc1];
        af2 = *(const bf16x8*)&Ac[(ar +  96) * 64 + pc1];
        af3 = *(const bf16x8*)&Ac[(ar + 112) * 64 + pc1];
        __builtin_amdgcn_s_setprio(1);
        MROW(4, af0) MROW(5, af1) MROW(6, af2) MROW(7, af3)
        __builtin_amdgcn_s_setprio(0);

        BAR();        // compute done -> next iter may overwrite slot nxt
    }
#undef MROW

    // ---- epilogue: co-row-major store order (R3's verified WRITE_SIZE fix) ----
    unsigned rj[4]; unsigned bj[4];
#pragma unroll
    for (int j = 0; j < 4; ++j) {
        unsigned n = n0 + wcol * 64 + j * 16 + r16;
        bj[j] = n / NSPAT; rj[j] = n - bj[j] * NSPAT;
    }
#pragma unroll
    for (int i = 0; i < 8; ++i) {
        int co_base = wrow * 128 + i * 16 + quad * 4;
        float4 bv = *(const float4*)(bias + co_base);
        float bvd[4] = {bv.x, bv.y, bv.z, bv.w};
#pragma unroll
        for (int d = 0; d < 4; ++d) {
#pragma unroll
            for (int j = 0; j < 4; ++j) {
                out[((size_t)(bj[j] * COUT + co_base + d)) * NSPAT + rj[j]] =
                    acc[i][j][d] + bvd[d];
            }
        }
    }
}

extern "C" void kernel_launch(void* const* d_in, const int* in_sizes, int n_in,
                              void* d_out, int out_size, void* d_ws, size_t ws_size,
                              hipStream_t stream) {
    const float* x      = (const float*)d_in[0];
    const float* weight = (const float*)d_in[1];
    const float* bias   = (const float*)d_in[2];
    const float* wp     = (const float*)d_in[3];
    const float* wn     = (const float*)d_in[4];
    float* out          = (float*)d_out;

    // ws layout: [0,1024) blockmax fp32[256] | [1024,..) qw bf16 [256][1152]
    //            [590848,..) x_t bf16 [64][56][56][128]
    float*          bmax = (float*)d_ws;
    unsigned short* qw   = (unsigned short*)((char*)d_ws + 1024);
    unsigned short* xt   = (unsigned short*)((char*)d_ws + 590848);

    maxabs_kernel<<<256, 256, 0, stream>>>(weight, bmax, COUT * KDIM);
    quant_kernel<<<(COUT * KDIM) / 256, 256, 0, stream>>>(weight, wp, wn, bmax, qw);
    cast_nhwc_kernel<<<BATCH * HIN, 256, 0, stream>>>(x, (unsigned*)xt);
    conv_mfma_kernel<<<NBLK, 512, 0, stream>>>(xt, qw, bias, out);
}

// Round 5
// 387.028 us; speedup vs baseline: 1.0199x; 1.0199x over previous
//
#include <hip/hip_runtime.h>
#include <hip/hip_bf16.h>

// Problem constants
#define BATCH 64
#define CIN   128
#define HIN   56
#define WIN   56
#define COUT  256
#define KSZ   3
#define OHP   54
#define OWP   54
#define NSPAT (OHP * OWP)          // 2916 flat spatial outputs per batch
#define NTILES 23                  // ceil(2916/128)
#define KDIM  (CIN * KSZ * KSZ)    // 1152

typedef short bf16x8 __attribute__((ext_vector_type(8)));
typedef float f32x4  __attribute__((ext_vector_type(4)));

static __device__ __forceinline__ unsigned short f2bf(float f) {
    unsigned v = __float_as_uint(f);
    v += 0x7FFFu + ((v >> 16) & 1u);
    return (unsigned short)(v >> 16);
}

static __device__ __forceinline__ void gl_lds16(const void* g, void* l) {
    __builtin_amdgcn_global_load_lds(
        (const __attribute__((address_space(1))) void*)g,
        (__attribute__((address_space(3))) void*)l, 16, 0, 0);
}

// ---------------- kernel 1: per-block max |w| (no atomics, no init needed) ----------------
__global__ __launch_bounds__(256) void maxabs_kernel(const float* __restrict__ w,
                                                     float* __restrict__ blockmax, int n) {
    float m = 0.f;
    for (int i = blockIdx.x * 256 + threadIdx.x; i < n; i += gridDim.x * 256)
        m = fmaxf(m, fabsf(w[i]));
    for (int off = 32; off > 0; off >>= 1)
        m = fmaxf(m, __shfl_down(m, off));
    __shared__ float red[4];
    if ((threadIdx.x & 63) == 0) red[threadIdx.x >> 6] = m;
    __syncthreads();
    if (threadIdx.x == 0)
        blockmax[blockIdx.x] = fmaxf(fmaxf(red[0], red[1]), fmaxf(red[2], red[3]));
}

// ---------------- kernel 2: finish max-reduce + ternary quantize + repack ----------------
// qw layout: [co][(kh*3+kw)*128 + ci] bf16
__global__ __launch_bounds__(256) void quant_kernel(const float* __restrict__ w,
                                                    const float* __restrict__ wp,
                                                    const float* __restrict__ wn,
                                                    const float* __restrict__ blockmax,
                                                    unsigned short* __restrict__ qw) {
    __shared__ float red[4];
    float m = blockmax[threadIdx.x];          // 256 partial maxima
    for (int off = 32; off > 0; off >>= 1)
        m = fmaxf(m, __shfl_down(m, off));
    if ((threadIdx.x & 63) == 0) red[threadIdx.x >> 6] = m;
    __syncthreads();
    float t = 0.05f * fmaxf(fmaxf(red[0], red[1]), fmaxf(red[2], red[3]));

    int idx = blockIdx.x * 256 + threadIdx.x;   // grid covers exactly 294912
    float p = fabsf(wp[0]), nn = fabsf(wn[0]);
    float v = w[idx];
    float q = (v > t) ? p : ((v < -t) ? -nn : 0.0f);
    int co  = idx / KDIM;
    int rem = idx - co * KDIM;
    int ci  = rem / 9;
    int kk  = rem - ci * 9;            // kh*3+kw
    qw[co * KDIM + kk * CIN + ci] = f2bf(q);
}

// ---------------- kernel 3: x fp32 NCHW -> bf16 NHWC (x_t[b][h][w][ci]) ----------------
// REWRITTEN (R5): old version was LDS-scalar-op bound (~900 scalar LDS wave-ops/block,
// 4-way read conflicts -> ~39 us = measured). Now: convert to bf16 BEFORE LDS (half
// bytes), stage [56][136] bf16 (16B-aligned rows), ds_write_b64 (4ci x 1w per op,
// 1 LDS write per global load), ds_read_b128 (8ci) + uint4 global stores (256B
// contiguous per 16 lanes). ~42 LDS wave-ops/block -> HBM-bound (~77MB, expect ~14us).
__global__ __launch_bounds__(256) void cast_nhwc_kernel(const float* __restrict__ x,
                                                        unsigned short* __restrict__ xt) {
    int b = blockIdx.x / HIN;
    int h = blockIdx.x - b * HIN;
    __shared__ __align__(16) unsigned short xsb[56][136];   // [w][ci], 272B rows (16B mult)

    // phase 1: 448 tasks; task t = (cig = t/14, wg = t%14): read 4 float4
    // (rows ci0..ci0+3, cols w0..w0+3; lanes 0..13 cover one ci row -> 224B contiguous),
    // convert, write 4 x ds_write_b64 at [w0+k][ci0] (8B-aligned: 272*w + 8*cig).
    for (int t = threadIdx.x; t < 448; t += 256) {
        int cig = t / 14, wg = t - cig * 14;
        int ci0 = cig * 4, w0 = wg * 4;
        const float* xp = x + ((size_t)(b * CIN + ci0) * HIN + h) * WIN + w0;
        float4 v0 = *(const float4*)(xp);
        float4 v1 = *(const float4*)(xp + (size_t)HIN * WIN);
        float4 v2 = *(const float4*)(xp + 2 * (size_t)HIN * WIN);
        float4 v3 = *(const float4*)(xp + 3 * (size_t)HIN * WIN);
        float a0[4] = {v0.x, v0.y, v0.z, v0.w};
        float a1[4] = {v1.x, v1.y, v1.z, v1.w};
        float a2[4] = {v2.x, v2.y, v2.z, v2.w};
        float a3[4] = {v3.x, v3.y, v3.z, v3.w};
#pragma unroll
        for (int k = 0; k < 4; ++k) {
            uint2 u;
            u.x = (unsigned)f2bf(a0[k]) | ((unsigned)f2bf(a1[k]) << 16);
            u.y = (unsigned)f2bf(a2[k]) | ((unsigned)f2bf(a3[k]) << 16);
            *(uint2*)&xsb[w0 + k][ci0] = u;
        }
    }
    __syncthreads();

    // phase 2: 896 tasks; task id = (w = id/16, cq = id%16): ds_read_b128 of 8 ci,
    // uint4 store to xt (16 lanes -> 256B contiguous; wave -> 1KB contiguous).
    for (int id = threadIdx.x; id < 896; id += 256) {
        int w_ = id >> 4, cq = id & 15;
        uint4 val = *(const uint4*)&xsb[w_][cq * 8];
        *(uint4*)&xt[((size_t)(b * HIN + h) * WIN + w_) * CIN + cq * 8] = val;
    }
}

// ---------------- kernel 4: implicit-GEMM MFMA conv ----------------
// BM=128 (co), BN=128 (flat spatial), BK=64; 18 K-iters, 32 MFMA/iter.
// grid = 2944 = 8 XCD x 368; blocks sharing b pinned to one XCD (b%8 == blockIdx%8).
// R3-verbatim (proven 122.5us, 81% of its LDS-BW bound): 3 blocks/CU hides barrier
// drain; co-row-major epilogue store order (WRITE_SIZE 285->190MB, verified R3).
__global__ __launch_bounds__(256, 3) void conv_mfma_kernel(const unsigned short* __restrict__ xt,
                                                           const unsigned short* __restrict__ qw,
                                                           const float* __restrict__ bias,
                                                           float* __restrict__ out) {
    int xcd = blockIdx.x & 7;
    int k   = blockIdx.x >> 3;          // 0..367
    int g   = k / 46;                   // 0..7
    int r   = k - g * 46;               // 0..45
    int b   = g * 8 + xcd;
    int mt  = r / 23;
    int nt  = r - mt * 23;

    __shared__ __align__(16) unsigned short As[128 * 64];   // [row][64] rows = co
    __shared__ __align__(16) unsigned short Bs[128 * 64];   // [row][64] rows = flat n

    int t    = threadIdx.x;
    int wave = t >> 6, lane = t & 63;
    int wm   = wave >> 1, wcol = wave & 1;
    int quad = lane >> 4, r16 = lane & 15;

    // staging: call c stages chunk p = c*256 + t; row = p>>3 = c*32 + (t>>3),
    // phys chunk-in-row = t&7, fetched logical chunk = (t&7) ^ (row&7)  [XOR-8 swizzle]
    int row0 = t >> 3;                         // 0..31
    int lc   = (t & 7) ^ (row0 & 7);           // c*32 doesn't change row&7

    const unsigned short* Ab = qw + (size_t)(mt * 128 + row0) * KDIM + lc * 8;
    const unsigned short* Bb[4];
#pragma unroll
    for (int c = 0; c < 4; ++c) {
        unsigned n = nt * 128 + c * 32 + row0;
        if (n > NSPAT - 1) n = NSPAT - 1;
        unsigned oh = n / OWP, ow = n - oh * OWP;
        Bb[c] = xt + ((size_t)(b * HIN + oh) * WIN + ow) * CIN + lc * 8;
    }

    f32x4 acc[4][4] = {};

#pragma unroll
    for (int kk = 0; kk < 18; ++kk) {
        int slice = kk >> 1;
        int kh = slice / 3, kw = slice - kh * 3;
        int boff = (kh * WIN + kw) * CIN + (kk & 1) * 64;   // shorts
        int aoff = kk * 64;                                 // shorts

#pragma unroll
        for (int c = 0; c < 4; ++c) {
            gl_lds16(Ab + aoff + c * 32 * KDIM, (char*)As + c * 4096 + wave * 1024);
            gl_lds16(Bb[c] + boff,              (char*)Bs + c * 4096 + wave * 1024);
        }
        __syncthreads();

#pragma unroll
        for (int s = 0; s < 2; ++s) {
            int pc = ((s * 4 + quad) ^ (r16 & 7)) * 8;      // phys chunk offset (shorts)
            bf16x8 af[4], bfr[4];
#pragma unroll
            for (int i = 0; i < 4; ++i)
                af[i] = *(const bf16x8*)&As[(wm * 64 + i * 16 + r16) * 64 + pc];
#pragma unroll
            for (int j = 0; j < 4; ++j)
                bfr[j] = *(const bf16x8*)&Bs[(wcol * 64 + j * 16 + r16) * 64 + pc];
#pragma unroll
            for (int i = 0; i < 4; ++i)
#pragma unroll
                for (int j = 0; j < 4; ++j)
                    acc[i][j] = __builtin_amdgcn_mfma_f32_16x16x32_bf16(af[i], bfr[j], acc[i][j], 0, 0, 0);
        }
        __syncthreads();
    }

    // ---- epilogue: D row m = quad*4 + r, col n = r16 (layout verified R1) ----
    // co-row-major store order: each wave emits 256B contiguous per output row
    // back-to-back -> full 128B lines complete in L2 (WRITE_SIZE fix, verified R3).
#pragma unroll
    for (int i = 0; i < 4; ++i) {
        int co_base = mt * 128 + wm * 64 + i * 16 + quad * 4;
        float4 bv = *(const float4*)(bias + co_base);
        float bvd[4] = {bv.x, bv.y, bv.z, bv.w};
#pragma unroll
        for (int d = 0; d < 4; ++d) {
            size_t rowb = (size_t)(b * COUT + co_base + d) * NSPAT;
#pragma unroll
            for (int j = 0; j < 4; ++j) {
                unsigned n = nt * 128 + wcol * 64 + j * 16 + r16;
                if (n < NSPAT)
                    out[rowb + n] = acc[i][j][d] + bvd[d];
            }
        }
    }
}

extern "C" void kernel_launch(void* const* d_in, const int* in_sizes, int n_in,
                              void* d_out, int out_size, void* d_ws, size_t ws_size,
                              hipStream_t stream) {
    const float* x      = (const float*)d_in[0];
    const float* weight = (const float*)d_in[1];
    const float* bias   = (const float*)d_in[2];
    const float* wp     = (const float*)d_in[3];
    const float* wn     = (const float*)d_in[4];
    float* out          = (float*)d_out;

    // ws layout: [0,1024) blockmax fp32[256] | [1024,..) qw bf16 [256][1152]
    //            [590848,..) x_t bf16 [64][56][56][128]
    float*          bmax = (float*)d_ws;
    unsigned short* qw   = (unsigned short*)((char*)d_ws + 1024);
    unsigned short* xt   = (unsigned short*)((char*)d_ws + 590848);

    maxabs_kernel<<<256, 256, 0, stream>>>(weight, bmax, COUT * KDIM);
    quant_kernel<<<(COUT * KDIM) / 256, 256, 0, stream>>>(weight, wp, wn, bmax, qw);
    cast_nhwc_kernel<<<BATCH * HIN, 256, 0, stream>>>(x, xt);
    conv_mfma_kernel<<<2 * BATCH * NTILES, 256, 0, stream>>>(xt, qw, bias, out);
}

// Round 6
// 384.280 us; speedup vs baseline: 1.0272x; 1.0071x over previous
//
#include <hip/hip_runtime.h>
#include <hip/hip_bf16.h>

// Problem constants
#define BATCH 64
#define CIN   128
#define HIN   56
#define WIN   56
#define COUT  256
#define KSZ   3
#define OHP   54
#define OWP   54
#define NSPAT (OHP * OWP)          // 2916 flat spatial outputs per batch
#define NFLAT (BATCH * NSPAT)      // 186624 = 972 * 192 exactly
#define KDIM  (CIN * KSZ * KSZ)    // 1152
#define NTILE 972                  // NFLAT / 192
#define NBLK2 1944                 // 2 * NTILE  (mt in {0,1})

typedef short bf16x8 __attribute__((ext_vector_type(8)));
typedef float f32x4  __attribute__((ext_vector_type(4)));

static __device__ __forceinline__ unsigned short f2bf(float f) {
    unsigned v = __float_as_uint(f);
    v += 0x7FFFu + ((v >> 16) & 1u);
    return (unsigned short)(v >> 16);
}

static __device__ __forceinline__ void gl_lds16(const void* g, void* l) {
    __builtin_amdgcn_global_load_lds(
        (const __attribute__((address_space(1))) void*)g,
        (__attribute__((address_space(3))) void*)l, 16, 0, 0);
}

// ---------------- kernel 1: per-block max |w| (no atomics, no init needed) ----------------
__global__ __launch_bounds__(256) void maxabs_kernel(const float* __restrict__ w,
                                                     float* __restrict__ blockmax, int n) {
    float m = 0.f;
    for (int i = blockIdx.x * 256 + threadIdx.x; i < n; i += gridDim.x * 256)
        m = fmaxf(m, fabsf(w[i]));
    for (int off = 32; off > 0; off >>= 1)
        m = fmaxf(m, __shfl_down(m, off));
    __shared__ float red[4];
    if ((threadIdx.x & 63) == 0) red[threadIdx.x >> 6] = m;
    __syncthreads();
    if (threadIdx.x == 0)
        blockmax[blockIdx.x] = fmaxf(fmaxf(red[0], red[1]), fmaxf(red[2], red[3]));
}

// ---------------- kernel 2: finish max-reduce + ternary quantize + repack ----------------
// qw layout: [co][(kh*3+kw)*128 + ci] bf16
__global__ __launch_bounds__(256) void quant_kernel(const float* __restrict__ w,
                                                    const float* __restrict__ wp,
                                                    const float* __restrict__ wn,
                                                    const float* __restrict__ blockmax,
                                                    unsigned short* __restrict__ qw) {
    __shared__ float red[4];
    float m = blockmax[threadIdx.x];          // 256 partial maxima
    for (int off = 32; off > 0; off >>= 1)
        m = fmaxf(m, __shfl_down(m, off));
    if ((threadIdx.x & 63) == 0) red[threadIdx.x >> 6] = m;
    __syncthreads();
    float t = 0.05f * fmaxf(fmaxf(red[0], red[1]), fmaxf(red[2], red[3]));

    int idx = blockIdx.x * 256 + threadIdx.x;   // grid covers exactly 294912
    float p = fabsf(wp[0]), nn = fabsf(wn[0]);
    float v = w[idx];
    float q = (v > t) ? p : ((v < -t) ? -nn : 0.0f);
    int co  = idx / KDIM;
    int rem = idx - co * KDIM;
    int ci  = rem / 9;
    int kk  = rem - ci * 9;            // kh*3+kw
    qw[co * KDIM + kk * CIN + ci] = f2bf(q);
}

// ---------------- kernel 3: x fp32 NCHW -> bf16 NHWC (x_t[b][h][w][ci]) ----------------
// (R5 version: bf16-before-LDS, ds_write_b64 / ds_read_b128, vectorized stores.)
__global__ __launch_bounds__(256) void cast_nhwc_kernel(const float* __restrict__ x,
                                                        unsigned short* __restrict__ xt) {
    int b = blockIdx.x / HIN;
    int h = blockIdx.x - b * HIN;
    __shared__ __align__(16) unsigned short xsb[56][136];   // [w][ci], 272B rows (16B mult)

    for (int t = threadIdx.x; t < 448; t += 256) {
        int cig = t / 14, wg = t - cig * 14;
        int ci0 = cig * 4, w0 = wg * 4;
        const float* xp = x + ((size_t)(b * CIN + ci0) * HIN + h) * WIN + w0;
        float4 v0 = *(const float4*)(xp);
        float4 v1 = *(const float4*)(xp + (size_t)HIN * WIN);
        float4 v2 = *(const float4*)(xp + 2 * (size_t)HIN * WIN);
        float4 v3 = *(const float4*)(xp + 3 * (size_t)HIN * WIN);
        float a0[4] = {v0.x, v0.y, v0.z, v0.w};
        float a1[4] = {v1.x, v1.y, v1.z, v1.w};
        float a2[4] = {v2.x, v2.y, v2.z, v2.w};
        float a3[4] = {v3.x, v3.y, v3.z, v3.w};
#pragma unroll
        for (int k = 0; k < 4; ++k) {
            uint2 u;
            u.x = (unsigned)f2bf(a0[k]) | ((unsigned)f2bf(a1[k]) << 16);
            u.y = (unsigned)f2bf(a2[k]) | ((unsigned)f2bf(a3[k]) << 16);
            *(uint2*)&xsb[w0 + k][ci0] = u;
        }
    }
    __syncthreads();

    for (int id = threadIdx.x; id < 896; id += 256) {
        int w_ = id >> 4, cq = id & 15;
        uint4 val = *(const uint4*)&xsb[w_][cq * 8];
        *(uint4*)&xt[((size_t)(b * HIN + h) * WIN + w_) * CIN + cq * 8] = val;
    }
}

// ---------------- kernel 4: implicit-GEMM MFMA conv, BM=128 x BN=192 ----------------
// R6: same PROVEN structure as R3 (single-buffer, 2x __syncthreads per K-tile,
// 3 blocks/CU, XOR-8 swizzle, co-row-major epilogue) but wave-tile 64x96 instead of
// 64x64: per-output LDS traffic x0.84 (the measured bottleneck at 81% of LDS bound).
// acc[4][6] = 96 AGPR + ~60 VGPR ~= 156 unified <= 170 -> still 3 waves/SIMD
// (the failed 128x64-wave kernels needed ~192 -> 2/SIMD -> latency wall).
// N flattened across batches: 186624 = 972*192 exact, no bounds checks.
// Grid 1944 = 8 XCD x 243: wgid = xcd*243 + loc -> contiguous n-range per XCD.
__global__ __launch_bounds__(256, 3) void conv_mfma_kernel(const unsigned short* __restrict__ xt,
                                                           const unsigned short* __restrict__ qw,
                                                           const float* __restrict__ bias,
                                                           float* __restrict__ out) {
    unsigned orig = blockIdx.x;
    unsigned wgid = (orig & 7u) * 243u + (orig >> 3);   // bijective: 1944 % 8 == 0
    int mt    = wgid / NTILE;            // 0..1  (co half)
    int ntile = wgid - mt * NTILE;       // 0..971
    unsigned n0 = ntile * 192u;

    __shared__ __align__(16) unsigned short As[128 * 64];   // 16 KB, rows = co
    __shared__ __align__(16) unsigned short Bs[192 * 64];   // 24 KB, rows = flat n

    int t    = threadIdx.x;
    int wave = t >> 6, lane = t & 63;
    int wm   = wave >> 1, wcol = wave & 1;   // 2M x 2N waves; wave tile 64co x 96n
    int quad = lane >> 4, r16 = lane & 15;

    // staging: call c stages chunk p = c*256 + t; row = c*32 + (t>>3),
    // phys chunk-in-row = t&7, fetched logical chunk = (t&7) ^ (row&7)  [XOR-8 swizzle]
    int row_s = t >> 3;                        // 0..31
    int lc    = (t & 7) ^ (row_s & 7);         // c*32 doesn't change row&7

    const unsigned short* Ab = qw + (size_t)(mt * 128 + row_s) * KDIM + lc * 8;
    const unsigned short* Bg[6];
#pragma unroll
    for (int c = 0; c < 6; ++c) {
        unsigned n = n0 + c * 32 + row_s;            // < 186624 always (exact tiling)
        unsigned b = n / NSPAT, rem = n - b * NSPAT;
        unsigned oh = rem / OWP, ow = rem - oh * OWP;
        Bg[c] = xt + ((size_t)((b * HIN + oh) * WIN + ow)) * CIN + lc * 8;
    }

    f32x4 acc[4][6] = {};

#pragma unroll
    for (int kk = 0; kk < 18; ++kk) {
        int slice = kk >> 1;
        int kh = slice / 3, kw = slice - kh * 3;
        int boff = (kh * WIN + kw) * CIN + (kk & 1) * 64;   // shorts
        int aoff = kk * 64;                                 // shorts

#pragma unroll
        for (int c = 0; c < 4; ++c)
            gl_lds16(Ab + aoff + c * 32 * KDIM, (char*)As + c * 4096 + wave * 1024);
#pragma unroll
        for (int c = 0; c < 6; ++c)
            gl_lds16(Bg[c] + boff,              (char*)Bs + c * 4096 + wave * 1024);
        __syncthreads();

#pragma unroll
        for (int s = 0; s < 2; ++s) {
            int pc = ((s * 4 + quad) ^ (r16 & 7)) * 8;      // phys chunk offset (shorts)
            bf16x8 af[4], bfr[6];
#pragma unroll
            for (int i = 0; i < 4; ++i)
                af[i] = *(const bf16x8*)&As[(wm * 64 + i * 16 + r16) * 64 + pc];
#pragma unroll
            for (int j = 0; j < 6; ++j)
                bfr[j] = *(const bf16x8*)&Bs[(wcol * 96 + j * 16 + r16) * 64 + pc];
#pragma unroll
            for (int i = 0; i < 4; ++i)
#pragma unroll
                for (int j = 0; j < 6; ++j)
                    acc[i][j] = __builtin_amdgcn_mfma_f32_16x16x32_bf16(af[i], bfr[j], acc[i][j], 0, 0, 0);
        }
        __syncthreads();
    }

    // ---- epilogue: D row m = quad*4 + r, col n = r16; co-row-major store order
    // (R3's verified WRITE_SIZE fix: 256B+ contiguous per output row per wave) ----
    unsigned bj[6], rj[6];
#pragma unroll
    for (int j = 0; j < 6; ++j) {
        unsigned n = n0 + wcol * 96 + j * 16 + r16;
        bj[j] = n / NSPAT; rj[j] = n - bj[j] * NSPAT;
    }
#pragma unroll
    for (int i = 0; i < 4; ++i) {
        int co_base = mt * 128 + wm * 64 + i * 16 + quad * 4;
        float4 bv = *(const float4*)(bias + co_base);
        float bvd[4] = {bv.x, bv.y, bv.z, bv.w};
#pragma unroll
        for (int d = 0; d < 4; ++d) {
#pragma unroll
            for (int j = 0; j < 6; ++j)
                out[((size_t)(bj[j] * COUT + co_base + d)) * NSPAT + rj[j]] =
                    acc[i][j][d] + bvd[d];
        }
    }
}

extern "C" void kernel_launch(void* const* d_in, const int* in_sizes, int n_in,
                              void* d_out, int out_size, void* d_ws, size_t ws_size,
                              hipStream_t stream) {
    const float* x      = (const float*)d_in[0];
    const float* weight = (const float*)d_in[1];
    const float* bias   = (const float*)d_in[2];
    const float* wp     = (const float*)d_in[3];
    const float* wn     = (const float*)d_in[4];
    float* out          = (float*)d_out;

    // ws layout: [0,1024) blockmax fp32[256] | [1024,..) qw bf16 [256][1152]
    //            [590848,..) x_t bf16 [64][56][56][128]
    float*          bmax = (float*)d_ws;
    unsigned short* qw   = (unsigned short*)((char*)d_ws + 1024);
    unsigned short* xt   = (unsigned short*)((char*)d_ws + 590848);

    maxabs_kernel<<<256, 256, 0, stream>>>(weight, bmax, COUT * KDIM);
    quant_kernel<<<(COUT * KDIM) / 256, 256, 0, stream>>>(weight, wp, wn, bmax, qw);
    cast_nhwc_kernel<<<BATCH * HIN, 256, 0, stream>>>(x, xt);
    conv_mfma_kernel<<<NBLK2, 256, 0, stream>>>(xt, qw, bias, out);
}